// Round 1
// baseline (18.880 us; speedup 1.0000x reference)
//
#include <hip/hip_runtime.h>

// q[n] = v(n)^T M v(n), v = degree-2 Veronese of xh = [1, x0..x5].
// x layout: reference does x.reshape(6, N) on a row-major (N,6) array ->
// pure flat reshape: row d of xv is x_flat[d*N .. d*N+N-1]. Coalesced reads.
// M is symmetric (A A^T + I): use q = sum_j Mjj vj^2 + 2 sum_{j<k} Mjk vj vk.

__global__ void qform_kernel(const float* __restrict__ x,
                             const float* __restrict__ M,
                             float* __restrict__ out, int N)
{
    int n = blockIdx.x * blockDim.x + threadIdx.x;
    if (n >= N) return;

    float xh[7];
    xh[0] = 1.0f;
    #pragma unroll
    for (int d = 0; d < 6; ++d)
        xh[d + 1] = x[(size_t)d * (size_t)N + n];

    // Veronese in combinations_with_replacement(range(7), 2) order:
    // (0,0),(0,1),...,(0,6),(1,1),...,(6,6) -> 28 entries.
    float v[28];
    {
        int vi = 0;
        #pragma unroll
        for (int a = 0; a < 7; ++a)
            #pragma unroll
            for (int b = a; b < 7; ++b)
                v[vi++] = xh[a] * xh[b];
    }

    // Symmetric quadratic form, upper triangle only.
    float qd = 0.0f;   // sum_j M[j][j] * v[j]^2
    float qo = 0.0f;   // sum_{j<k} M[j][k] * v[j] * v[k]
    #pragma unroll
    for (int j = 0; j < 28; ++j) {
        qd = fmaf(M[j * 28 + j], v[j] * v[j], qd);
        float t = 0.0f;
        #pragma unroll
        for (int k = j + 1; k < 28; ++k)
            t = fmaf(M[j * 28 + k], v[k], t);
        qo = fmaf(v[j], t, qo);
    }
    out[n] = fmaf(2.0f, qo, qd);
}

extern "C" void kernel_launch(void* const* d_in, const int* in_sizes, int n_in,
                              void* d_out, int out_size, void* d_ws, size_t ws_size,
                              hipStream_t stream)
{
    const float* x   = (const float*)d_in[0];   // 6*N floats (flat-reshaped)
    const float* M   = (const float*)d_in[1];   // 28*28 floats
    float* out       = (float*)d_out;           // N floats
    const int N      = out_size;                // 1,000,000

    const int block = 256;
    const int grid  = (N + block - 1) / block;
    qform_kernel<<<grid, block, 0, stream>>>(x, M, out, N);
}

// Round 2
// 15.064 us; speedup vs baseline: 1.2533x; 1.2533x over previous
//
#include <hip/hip_runtime.h>

// q[n] = v(n)^T M v(n), v = degree-2 Veronese of xh = [1, x0..x5].
// x layout: flat reshape of row-major (N,6) -> xv[d][n] = x_flat[d*N + n].
// M symmetric: q = sum_j Mjj vj^2 + 2 sum_{j<k} Mjk vj vk.
// 2 points/thread as float2 -> v_pk_fma_f32 packing + amortized scalar M loads.

typedef float f32x2 __attribute__((ext_vector_type(2)));

__global__ void qform2_kernel(const float* __restrict__ x,
                              const float* __restrict__ M,
                              float* __restrict__ out, int N2, int N)
{
    int t = blockIdx.x * blockDim.x + threadIdx.x;
    if (t >= N2) return;
    int n = 2 * t;

    f32x2 xh[7];
    xh[0] = (f32x2){1.0f, 1.0f};
    #pragma unroll
    for (int d = 0; d < 6; ++d)
        xh[d + 1] = *(const f32x2*)(x + (size_t)d * (size_t)N + n);

    // Veronese: combinations_with_replacement(range(7),2) order.
    f32x2 v[28];
    {
        int vi = 0;
        #pragma unroll
        for (int a = 0; a < 7; ++a)
            #pragma unroll
            for (int b = a; b < 7; ++b)
                v[vi++] = xh[a] * xh[b];
    }

    f32x2 qd = (f32x2){0.0f, 0.0f};   // sum_j M[j][j] * v[j]^2
    f32x2 qo = (f32x2){0.0f, 0.0f};   // sum_{j<k} M[j][k] * v[j] * v[k]
    #pragma unroll
    for (int j = 0; j < 28; ++j) {
        float mjj = M[j * 28 + j];
        f32x2 mjj2 = (f32x2){mjj, mjj};
        qd = __builtin_elementwise_fma(mjj2, v[j] * v[j], qd);
        f32x2 tt = (f32x2){0.0f, 0.0f};
        #pragma unroll
        for (int k = j + 1; k < 28; ++k) {
            float mjk = M[j * 28 + k];
            f32x2 m2 = (f32x2){mjk, mjk};
            tt = __builtin_elementwise_fma(m2, v[k], tt);
        }
        qo = __builtin_elementwise_fma(v[j], tt, qo);
    }
    f32x2 q = __builtin_elementwise_fma((f32x2){2.0f, 2.0f}, qo, qd);
    *(f32x2*)(out + n) = q;
}

extern "C" void kernel_launch(void* const* d_in, const int* in_sizes, int n_in,
                              void* d_out, int out_size, void* d_ws, size_t ws_size,
                              hipStream_t stream)
{
    const float* x   = (const float*)d_in[0];   // 6*N floats
    const float* M   = (const float*)d_in[1];   // 28*28 floats
    float* out       = (float*)d_out;           // N floats
    const int N      = out_size;                // 1,000,000 (even)
    const int N2     = N / 2;

    const int block = 256;
    const int grid  = (N2 + block - 1) / block;
    qform2_kernel<<<grid, block, 0, stream>>>(x, M, out, N2, N);
}